// Round 11
// baseline (308.167 us; speedup 1.0000x reference)
//
#include <hip/hip_runtime.h>

#define B_ 2
#define S_ 2048
#define E_ 1024
#define H_ 16
#define D_ 64
#define M_ (B_*S_)
#define K_ E_

typedef __attribute__((ext_vector_type(8))) short  short8;
typedef __attribute__((ext_vector_type(4))) float  f32x4;
typedef __attribute__((ext_vector_type(8))) unsigned short u16x8;
typedef __attribute__((ext_vector_type(4))) unsigned short u16x4;
typedef __attribute__((ext_vector_type(4))) unsigned int   u32x4;

// 0.125 * log2(e): folded into Q so scores arrive in exp2 domain
#define QSCALE 0.18033688011112042f

#if __has_builtin(__builtin_amdgcn_exp2f)
#define EXP2F(x) __builtin_amdgcn_exp2f(x)   // raw v_exp_f32 (R10: -18% VALUBusy)
#else
#define EXP2F(x) exp2f(x)
#endif

__device__ __forceinline__ unsigned short f2bf(float f) {   // RNE
    unsigned u = __float_as_uint(f);
    u += 0x7fffu + ((u >> 16) & 1u);
    return (unsigned short)(u >> 16);
}

__device__ __forceinline__ void gl_lds16(const ushort* g, ushort* l) {
    __builtin_amdgcn_global_load_lds((const __attribute__((address_space(1))) void*)g,
                                     (__attribute__((address_space(3))) void*)l,
                                     16, 0, 0);
}

// ---------------------------------------------------------------------------
// fp32 -> bf16 conversion (all inputs).
// ---------------------------------------------------------------------------
__global__ __launch_bounds__(256)
void cvt_all(const float* __restrict__ q, const float* __restrict__ k,
             const float* __restrict__ v, const float* __restrict__ wq,
             const float* __restrict__ wk, const float* __restrict__ wv,
             const float* __restrict__ wo, ushort* __restrict__ dst)
{
    const int bid = blockIdx.x;
    const float* src;
    size_t dof;
    int local;
    if (bid < 6144) {
        const int t = bid >> 11;
        src = (t == 0) ? q : (t == 1) ? k : v;
        dof = (size_t)t * 4194304u;
        local = bid & 2047;
    } else {
        const int r = bid - 6144;
        const int t = r >> 9;
        src = (t == 0) ? wq : (t == 1) ? wk : (t == 2) ? wv : wo;
        dof = 12582912u + (size_t)t * 1048576u;
        local = r & 511;
    }
    const size_t idx = (size_t)local * 2048 + threadIdx.x * 8;
    const float4 a = *(const float4*)(src + idx);
    const float4 b = *(const float4*)(src + idx + 4);
    u16x8 o;
    o[0] = f2bf(a.x); o[1] = f2bf(a.y); o[2] = f2bf(a.z); o[3] = f2bf(a.w);
    o[4] = f2bf(b.x); o[5] = f2bf(b.y); o[6] = f2bf(b.z); o[7] = f2bf(b.w);
    *(u16x8*)(dst + dof + idx) = o;
}

// ---------------------------------------------------------------------------
// m97 GEMM core. SWAP=0: acc = X.W^T (C rows = tokens). SWAP=1: operands
// swapped -> C rows = features (C^T), enabling d-contiguous bf16 stores.
// ---------------------------------------------------------------------------
template<int SWAP>
__device__ __forceinline__ void gemm_core(const ushort* __restrict__ X,
                                          const ushort* __restrict__ W,
                                          int m0, int n0,
                                          f32x4 acc[4][4],
                                          ushort* Ast, ushort* Bst)
{
    const int tid  = threadIdx.x;
    const int lane = tid & 63;
    const int w    = tid >> 6;
    const int wm   = w & 1, wn = w >> 1;
    const int r0   = tid >> 2;
    const int c8   = (tid & 3) * 8;

    const f32x4 zero = {0.f, 0.f, 0.f, 0.f};
    #pragma unroll
    for (int mt = 0; mt < 4; ++mt)
        #pragma unroll
        for (int nt = 0; nt < 4; ++nt) acc[mt][nt] = zero;

    const int kb = (lane >> 4) * 8;

    for (int k0 = 0; k0 < K_; k0 += 32) {
        __syncthreads();
        const ushort* ga = X + (size_t)(m0 + r0) * K_ + k0 + c8;
        gl_lds16(ga, Ast + tid * 8);
        gl_lds16(ga + (size_t)64 * K_, Ast + 2048 + tid * 8);
        const ushort* gb = W + (size_t)(n0 + r0) * K_ + k0 + c8;
        gl_lds16(gb, Bst + tid * 8);
        gl_lds16(gb + (size_t)64 * K_, Bst + 2048 + tid * 8);
        __syncthreads();

        short8 af[4], bf[4];
        #pragma unroll
        for (int mt = 0; mt < 4; ++mt)
            af[mt] = *(const short8*)(Ast + (wm * 64 + mt * 16 + (lane & 15)) * 32 + kb);
        #pragma unroll
        for (int nt = 0; nt < 4; ++nt)
            bf[nt] = *(const short8*)(Bst + (wn * 64 + nt * 16 + (lane & 15)) * 32 + kb);
        #pragma unroll
        for (int mt = 0; mt < 4; ++mt)
            #pragma unroll
            for (int nt = 0; nt < 4; ++nt) {
                if (SWAP)
                    acc[mt][nt] = __builtin_amdgcn_mfma_f32_16x16x32_bf16(bf[nt], af[mt], acc[mt][nt], 0, 0, 0);
                else
                    acc[mt][nt] = __builtin_amdgcn_mfma_f32_16x16x32_bf16(af[mt], bf[nt], acc[mt][nt], 0, 0, 0);
            }
    }
}

// ---------------------------------------------------------------------------
// QKV projections. z=0: Q -> [B,H,S,D] scaled by QSCALE (swapped, d-contig
// u16x4 stores). z=1: K -> [B,H,S,D] (swapped). z=2: V -> [B,H,D,S].
// ---------------------------------------------------------------------------
__global__ __launch_bounds__(256)
void gemm_qkv(const ushort* __restrict__ Xq, const ushort* __restrict__ Xk,
              const ushort* __restrict__ Xv, const ushort* __restrict__ Wq,
              const ushort* __restrict__ Wk, const ushort* __restrict__ Wv,
              const float* __restrict__ bq, const float* __restrict__ bk,
              const float* __restrict__ bv, ushort* __restrict__ Qh,
              ushort* __restrict__ Kh, ushort* __restrict__ Vt)
{
    __shared__ ushort Ast[128 * 32];
    __shared__ ushort Bst[128 * 32];
    const int z = blockIdx.z;
    const ushort* X = (z == 0) ? Xq : (z == 1) ? Xk : Xv;
    const ushort* W = (z == 0) ? Wq : (z == 1) ? Wk : Wv;
    const float* bias = (z == 0) ? bq : (z == 1) ? bk : bv;
    ushort* dst = (z == 0) ? Qh : (z == 1) ? Kh : Vt;

    const int m0 = blockIdx.y * 128, n0 = blockIdx.x * 128;
    f32x4 acc[4][4];
    const int lane = threadIdx.x & 63, w = threadIdx.x >> 6;
    const int wm = w & 1, wn = w >> 1;
    const int l15 = lane & 15, quad = lane >> 4;

    if (z < 2) {
        gemm_core<1>(X, W, m0, n0, acc, Ast, Bst);
        const float qsc = (z == 0) ? QSCALE : 1.0f;
        #pragma unroll
        for (int nt = 0; nt < 4; ++nt) {
            const int nb = n0 + wn * 64 + nt * 16 + quad * 4;   // feature dim
            const int h = nb >> 6, d0 = nb & 63;
            const float4 b4 = *(const float4*)(bias + nb);
            const float bb4[4] = {b4.x, b4.y, b4.z, b4.w};
            #pragma unroll
            for (int mt = 0; mt < 4; ++mt) {
                const int tok = m0 + wm * 64 + mt * 16 + l15;
                const int b = tok >> 11, s = tok & (S_ - 1);
                u16x4 pk;
                #pragma unroll
                for (int r = 0; r < 4; ++r)
                    pk[r] = f2bf((acc[mt][nt][r] + bb4[r]) * qsc);
                *(u16x4*)&dst[(((size_t)(b * H_ + h) * S_) + s) * D_ + d0] = pk;
            }
        }
    } else {
        gemm_core<0>(X, W, m0, n0, acc, Ast, Bst);
        float bias4[4];
        #pragma unroll
        for (int nt = 0; nt < 4; ++nt)
            bias4[nt] = bias[n0 + wn * 64 + nt * 16 + l15];
        #pragma unroll
        for (int mt = 0; mt < 4; ++mt) {
            const int mrow0 = m0 + wm * 64 + mt * 16 + (quad * 4);
            const int b = mrow0 >> 11;
            const int s0 = mrow0 & (S_ - 1);
            #pragma unroll
            for (int nt = 0; nt < 4; ++nt) {
                const int n = n0 + wn * 64 + nt * 16 + l15;
                const int h = n >> 6, d = n & 63;
                u16x4 pk;
                #pragma unroll
                for (int r = 0; r < 4; ++r) pk[r] = f2bf(acc[mt][nt][r] + bias4[nt]);
                *(u16x4*)&Vt[(((size_t)(b * H_ + h) * D_) + d) * S_ + s0] = pk;
            }
        }
    }
}

// ---------------------------------------------------------------------------
// Final projection: out(fp32) = AO . Wo^T + bo
// ---------------------------------------------------------------------------
__global__ __launch_bounds__(256)
void gemm_out(const ushort* __restrict__ X, const ushort* __restrict__ W,
              const float* __restrict__ bias, float* __restrict__ out)
{
    __shared__ ushort Ast[128 * 32];
    __shared__ ushort Bst[128 * 32];
    const int m0 = blockIdx.y * 128, n0 = blockIdx.x * 128;
    f32x4 acc[4][4];
    gemm_core<0>(X, W, m0, n0, acc, Ast, Bst);

    const int lane = threadIdx.x & 63, w = threadIdx.x >> 6;
    const int wm = w & 1, wn = w >> 1;
    float bias4[4];
    #pragma unroll
    for (int nt = 0; nt < 4; ++nt)
        bias4[nt] = bias[n0 + wn * 64 + nt * 16 + (lane & 15)];

    #pragma unroll
    for (int mt = 0; mt < 4; ++mt) {
        const int mrow0 = m0 + wm * 64 + mt * 16 + ((lane >> 4) * 4);
        #pragma unroll
        for (int nt = 0; nt < 4; ++nt) {
            const int n = n0 + wn * 64 + nt * 16 + (lane & 15);
            #pragma unroll
            for (int r = 0; r < 4; ++r)
                out[(size_t)(mrow0 + r) * E_ + n] = acc[mt][nt][r] + bias4[nt];
        }
    }
}

// ---------------------------------------------------------------------------
// Flash attention, PAIR-PV: kv loop unrolled by 2 tiles. Tile A's p fills
// A-frag k-slots j=0..3, tile B's fills j=4..7 -> ONE full-K=32 PV MFMA set
// per pair (halves PV MFMA count vs zero-padded). vb = {V_A rows, V_B rows}.
// Staging/barrier structure = R7 (coalesced gl_lds, 2 buffers, 1 barrier
// per tile); vvA/paLo carried in regs across the mid-pair barrier.
// launch_bounds(256,3): unified use ~164 < 170 cap -> 3 blocks/CU.
// Spill guard: WRITE_SIZE must stay 8 MB (R4/R5 lesson).
// No runtime indexing of per-thread arrays (scratch-demotion lesson).
// ---------------------------------------------------------------------------
#define NTILE (S_ / 64)
__global__ __launch_bounds__(256, 3)
void flash_mfma(const ushort* __restrict__ Qg, const ushort* __restrict__ Kg,
                const ushort* __restrict__ Vg, ushort* __restrict__ AO)
{
    // 40 KB: Qs(4096) | buf0: K(4096) V(4096) | buf1: K(4096) V(4096)
    __shared__ ushort sh[20480];
    ushort* Qs = sh;
    ushort* K0 = sh + 4096;
    ushort* V0 = sh + 8192;
    ushort* K1 = sh + 12288;
    ushort* V1 = sh + 16384;

    const int tid = threadIdx.x, lane = tid & 63, w = tid >> 6;
    const int l15 = lane & 15, quad = lane >> 4;
    const int q0 = blockIdx.x * 64, h = blockIdx.y, b = blockIdx.z;
    const size_t qk_off = (size_t)(b * H_ + h) * S_ * D_;   // [s][d]
    const size_t vt_off = (size_t)(b * H_ + h) * D_ * S_;   // [d][s]

    // ---- stage Q + K/V tile 0 (buf 0) together ----
    #pragma unroll
    for (int i = 0; i < 2; ++i) {
        const int chunk = w + i * 4;
        const int row = chunk * 8 + (lane >> 3);
        const int gcol = (lane & 7) ^ (row & 7);
        gl_lds16(Qg + qk_off + (size_t)(q0 + row) * D_ + gcol * 8,
                 Qs + chunk * 512 + lane * 8);
        gl_lds16(Kg + qk_off + (size_t)row * D_ + gcol * 8,
                 K0 + chunk * 512 + lane * 8);
        gl_lds16(Vg + vt_off + (size_t)row * S_ + gcol * 8,
                 V0 + chunk * 512 + lane * 8);
    }
    __syncthreads();

    // loop-invariant Q B-frags: qb[g][kt] for q-group g (rows g*16+l15)
    short8 qb[4][2];
    #pragma unroll
    for (int g = 0; g < 4; ++g)
        #pragma unroll
        for (int kt = 0; kt < 2; ++kt)
            qb[g][kt] = *(const short8*)&Qs[(g * 16 + l15) * 64 +
                                            (((kt * 4 + quad) ^ (l15 & 7)) * 8)];

    const f32x4 zero = {0.f, 0.f, 0.f, 0.f};
    f32x4 o[4][4];                         // o[g][nt]: O[q=g*16+quad*4+r][d=nt*16+l15]
    #pragma unroll
    for (int g = 0; g < 4; ++g)
        #pragma unroll
        for (int nt = 0; nt < 4; ++nt) o[g][nt] = zero;
    float lsum[4] = {0.f, 0.f, 0.f, 0.f};  // partial denom, q = g*16+l15

    const int krow = (w * 16 + l15) * 64;                // K frag row offset
    const int gidx = (2 * w + (quad >> 1)) ^ (l15 & 7);  // swizzled V group

    for (int jp = 0; jp < NTILE; jp += 2) {
        // ================= body A: tile jp (buf 0) =================
        short8 ka[2];
        #pragma unroll
        for (int kt = 0; kt < 2; ++kt)
            ka[kt] = *(const short8*)&K0[krow + (((kt * 4 + quad) ^ (l15 & 7)) * 8)];
        uint2 vvA[4];
        #pragma unroll
        for (int nt = 0; nt < 4; ++nt)
            vvA[nt] = *(const uint2*)&V0[(nt * 16 + l15) * 64 + gidx * 8 + (quad & 1) * 4];

        // prefetch tile jp+1 -> buf 1
        {
            const int j0n = (jp + 1) * 64;
            #pragma unroll
            for (int i = 0; i < 2; ++i) {
                const int chunk = w + i * 4;
                const int row = chunk * 8 + (lane >> 3);
                const int gcol = (lane & 7) ^ (row & 7);
                gl_lds16(Kg + qk_off + (size_t)(j0n + row) * D_ + gcol * 8,
                         K1 + chunk * 512 + lane * 8);
                gl_lds16(Vg + vt_off + (size_t)row * S_ + j0n + gcol * 8,
                         V1 + chunk * 512 + lane * 8);
            }
        }

        // QK A + exp + pack (lower half of pair A-frag)
        uint2 paLo[4];
        #pragma unroll
        for (int g = 0; g < 4; ++g) {
            f32x4 t;
            t = __builtin_amdgcn_mfma_f32_16x16x32_bf16(ka[0], qb[g][0], zero, 0, 0, 0);
            t = __builtin_amdgcn_mfma_f32_16x16x32_bf16(ka[1], qb[g][1], t, 0, 0, 0);
            const float p0 = EXP2F(t[0]), p1 = EXP2F(t[1]);
            const float p2 = EXP2F(t[2]), p3 = EXP2F(t[3]);
            lsum[g] += (p0 + p1) + (p2 + p3);
            const unsigned a0 = __float_as_uint(p0) + 0x8000u;
            const unsigned a1 = __float_as_uint(p1) + 0x8000u;
            const unsigned a2 = __float_as_uint(p2) + 0x8000u;
            const unsigned a3 = __float_as_uint(p3) + 0x8000u;
            paLo[g].x = (a1 & 0xffff0000u) | (a0 >> 16);
            paLo[g].y = (a3 & 0xffff0000u) | (a2 >> 16);
        }
        __syncthreads();   // buf1 loaded; everyone done with buf0

        // ================= body B: tile jp+1 (buf 1) =================
        #pragma unroll
        for (int kt = 0; kt < 2; ++kt)
            ka[kt] = *(const short8*)&K1[krow + (((kt * 4 + quad) ^ (l15 & 7)) * 8)];
        uint2 vvB[4];
        #pragma unroll
        for (int nt = 0; nt < 4; ++nt)
            vvB[nt] = *(const uint2*)&V1[(nt * 16 + l15) * 64 + gidx * 8 + (quad & 1) * 4];

        // prefetch tile jp+2 -> buf 0
        if (jp + 2 < NTILE) {
            const int j0n = (jp + 2) * 64;
            #pragma unroll
            for (int i = 0; i < 2; ++i) {
                const int chunk = w + i * 4;
                const int row = chunk * 8 + (lane >> 3);
                const int gcol = (lane & 7) ^ (row & 7);
                gl_lds16(Kg + qk_off + (size_t)(j0n + row) * D_ + gcol * 8,
                         K0 + chunk * 512 + lane * 8);
                gl_lds16(Vg + vt_off + (size_t)row * S_ + j0n + gcol * 8,
                         V0 + chunk * 512 + lane * 8);
            }
        }

        // QK B + exp + pack upper; assemble full-K pair A-frags
        short8 pa8[4];
        #pragma unroll
        for (int g = 0; g < 4; ++g) {
            f32x4 t;
            t = __builtin_amdgcn_mfma_f32_16x16x32_bf16(ka[0], qb[g][0], zero, 0, 0, 0);
            t = __builtin_amdgcn_mfma_f32_16x16x32_bf16(ka[1], qb[g][1], t, 0, 0, 0);
            const float p0 = EXP2F(t[0]), p1 = EXP2F(t[1]);
            const float p2 = EXP2F(t[2]), p3 = EXP2F(t[3]);
            lsum[g] += (p0 + p1) + (p2 + p3);
            const unsigned a0 = __float_as_uint(p0) + 0x8000u;
            const unsigned a1 = __float_as_uint(p1) + 0x8000u;
            const unsigned a2 = __float_as_uint(p2) + 0x8000u;
            const unsigned a3 = __float_as_uint(p3) + 0x8000u;
            u32x4 pk;
            pk[0] = paLo[g].x;
            pk[1] = paLo[g].y;
            pk[2] = (a1 & 0xffff0000u) | (a0 >> 16);
            pk[3] = (a3 & 0xffff0000u) | (a2 >> 16);
            pa8[g] = __builtin_bit_cast(short8, pk);
        }

        // PV (full K=32): vb = {V_A rows (k=0..3 slots), V_B rows (k=4..7)}
        #pragma unroll
        for (int nt = 0; nt < 4; ++nt) {
            u32x4 vk;
            vk[0] = vvA[nt].x; vk[1] = vvA[nt].y;
            vk[2] = vvB[nt].x; vk[3] = vvB[nt].y;
            const short8 vb8 = __builtin_bit_cast(short8, vk);
            #pragma unroll
            for (int g = 0; g < 4; ++g)
                o[g][nt] = __builtin_amdgcn_mfma_f32_16x16x32_bf16(pa8[g], vb8, o[g][nt], 0, 0, 0);
        }

        __syncthreads();   // buf0 (tile jp+2) loaded; everyone done with buf1
    }

    // ---- cross-wave reduction of O and l (kv was split across waves) ----
    #pragma unroll
    for (int g = 0; g < 4; ++g) {
        lsum[g] += __shfl_xor(lsum[g], 16);
        lsum[g] += __shfl_xor(lsum[g], 32);   // now quad-uniform
    }
    __syncthreads();
    float* fb = (float*)sh;                   // 10240 floats available
    #pragma unroll
    for (int g = 0; g < 4; ++g) {
        if (w != g) {
            #pragma unroll
            for (int nt = 0; nt < 4; ++nt)
                #pragma unroll
                for (int r = 0; r < 4; ++r)
                    fb[w * 1024 + (nt * 4 + r) * 64 + lane] = o[g][nt][r];
            if (quad == 0) fb[4096 + w * 64 + l15] = lsum[g];
        }
        __syncthreads();
        if (w == g) {
            #pragma unroll
            for (int ws = 0; ws < 4; ++ws) {
                if (ws == g) continue;
                #pragma unroll
                for (int nt = 0; nt < 4; ++nt)
                    #pragma unroll
                    for (int r = 0; r < 4; ++r)
                        o[g][nt][r] += fb[ws * 1024 + (nt * 4 + r) * 64 + lane];
                lsum[g] += fb[4096 + ws * 64 + l15];
            }
        }
        __syncthreads();
    }

    // Final store: wave g owns o[g]; wave-uniform branch, compile-time indices.
    #pragma unroll
    for (int g = 0; g < 4; ++g) {
        if (w == g) {
            const float inv = 1.0f / lsum[g];     // q = g*16 + l15
            float invr[4];
            #pragma unroll
            for (int r = 0; r < 4; ++r)
                invr[r] = __shfl(inv, (lane & 0x30) | (quad * 4 + r));
            #pragma unroll
            for (int nt = 0; nt < 4; ++nt) {
                const int e = h * 64 + nt * 16 + l15;
                #pragma unroll
                for (int r = 0; r < 4; ++r) {
                    const int s = q0 + g * 16 + quad * 4 + r;
                    AO[(size_t)(b * S_ + s) * E_ + e] = f2bf(o[g][nt][r] * invr[r]);
                }
            }
        }
    }
}

// ---------------------------------------------------------------------------
extern "C" void kernel_launch(void* const* d_in, const int* in_sizes, int n_in,
                              void* d_out, int out_size, void* d_ws, size_t ws_size,
                              hipStream_t stream) {
    const float* query = (const float*)d_in[0];
    const float* key   = (const float*)d_in[1];
    const float* value = (const float*)d_in[2];
    const float* Wq = (const float*)d_in[3];
    const float* bq = (const float*)d_in[4];
    const float* Wk = (const float*)d_in[5];
    const float* bk = (const float*)d_in[6];
    const float* Wv = (const float*)d_in[7];
    const float* bv = (const float*)d_in[8];
    const float* Wo = (const float*)d_in[9];
    const float* bo = (const float*)d_in[10];
    float* out = (float*)d_out;

    ushort* ws = (ushort*)d_ws;
    ushort* Xq  = ws;
    ushort* Xk  = ws + 4194304u;
    ushort* Xv  = ws + 8388608u;
    ushort* Wqb = ws + 12582912u;
    ushort* Wkb = ws + 13631488u;
    ushort* Wvb = ws + 14680064u;
    ushort* Wob = ws + 15728640u;
    ushort* Qh  = ws + 16777216u;          // [B,H,S,D] (pre-scaled by QSCALE)
    ushort* Kh  = ws + 20971520u;          // [B,H,S,D]
    ushort* Vt  = ws + 25165824u;          // [B,H,D,S]
    ushort* AO  = ws + 29360128u;          // [B,S,E]

    cvt_all<<<8192, 256, 0, stream>>>(query, key, value, Wq, Wk, Wv, Wo, ws);
    gemm_qkv<<<dim3(8, 32, 3), 256, 0, stream>>>(Xq, Xk, Xv, Wqb, Wkb, Wvb,
                                                 bq, bk, bv, Qh, Kh, Vt);
    flash_mfma<<<dim3(32, 16, 2), 256, 0, stream>>>(Qh, Kh, Vt, AO);
    gemm_out<<<dim3(8, 32, 1), 256, 0, stream>>>(AO, Wob, bo, out);
}

// Round 13
// 233.235 us; speedup vs baseline: 1.3213x; 1.3213x over previous
//
#include <hip/hip_runtime.h>

#define B_ 2
#define S_ 2048
#define E_ 1024
#define H_ 16
#define D_ 64
#define M_ (B_*S_)
#define K_ E_

typedef __attribute__((ext_vector_type(8))) short  short8;
typedef __attribute__((ext_vector_type(4))) float  f32x4;
typedef __attribute__((ext_vector_type(8))) unsigned short u16x8;
typedef __attribute__((ext_vector_type(4))) unsigned short u16x4;
typedef __attribute__((ext_vector_type(4))) unsigned int   u32x4;

// 0.125 * log2(e): folded into Q so scores arrive in exp2 domain
#define QSCALE 0.18033688011112042f

#if __has_builtin(__builtin_amdgcn_exp2f)
#define EXP2F(x) __builtin_amdgcn_exp2f(x)   // raw v_exp_f32 (R10: -18% VALUBusy)
#else
#define EXP2F(x) exp2f(x)
#endif

__device__ __forceinline__ unsigned short f2bf(float f) {   // RNE
    unsigned u = __float_as_uint(f);
    u += 0x7fffu + ((u >> 16) & 1u);
    return (unsigned short)(u >> 16);
}

__device__ __forceinline__ void gl_lds16(const ushort* g, ushort* l) {
    __builtin_amdgcn_global_load_lds((const __attribute__((address_space(1))) void*)g,
                                     (__attribute__((address_space(3))) void*)l,
                                     16, 0, 0);
}

// ---------------------------------------------------------------------------
// fp32 -> bf16 conversion (all inputs).
// ---------------------------------------------------------------------------
__global__ __launch_bounds__(256)
void cvt_all(const float* __restrict__ q, const float* __restrict__ k,
             const float* __restrict__ v, const float* __restrict__ wq,
             const float* __restrict__ wk, const float* __restrict__ wv,
             const float* __restrict__ wo, ushort* __restrict__ dst)
{
    const int bid = blockIdx.x;
    const float* src;
    size_t dof;
    int local;
    if (bid < 6144) {
        const int t = bid >> 11;
        src = (t == 0) ? q : (t == 1) ? k : v;
        dof = (size_t)t * 4194304u;
        local = bid & 2047;
    } else {
        const int r = bid - 6144;
        const int t = r >> 9;
        src = (t == 0) ? wq : (t == 1) ? wk : (t == 2) ? wv : wo;
        dof = 12582912u + (size_t)t * 1048576u;
        local = r & 511;
    }
    const size_t idx = (size_t)local * 2048 + threadIdx.x * 8;
    const float4 a = *(const float4*)(src + idx);
    const float4 b = *(const float4*)(src + idx + 4);
    u16x8 o;
    o[0] = f2bf(a.x); o[1] = f2bf(a.y); o[2] = f2bf(a.z); o[3] = f2bf(a.w);
    o[4] = f2bf(b.x); o[5] = f2bf(b.y); o[6] = f2bf(b.z); o[7] = f2bf(b.w);
    *(u16x8*)(dst + dof + idx) = o;
}

// ---------------------------------------------------------------------------
// m97 GEMM core. SWAP=0: acc = X.W^T (C rows = tokens). SWAP=1: operands
// swapped -> C rows = features (C^T), enabling d-contiguous bf16 stores.
// ---------------------------------------------------------------------------
template<int SWAP>
__device__ __forceinline__ void gemm_core(const ushort* __restrict__ X,
                                          const ushort* __restrict__ W,
                                          int m0, int n0,
                                          f32x4 acc[4][4],
                                          ushort* Ast, ushort* Bst)
{
    const int tid  = threadIdx.x;
    const int lane = tid & 63;
    const int w    = tid >> 6;
    const int wm   = w & 1, wn = w >> 1;
    const int r0   = tid >> 2;
    const int c8   = (tid & 3) * 8;

    const f32x4 zero = {0.f, 0.f, 0.f, 0.f};
    #pragma unroll
    for (int mt = 0; mt < 4; ++mt)
        #pragma unroll
        for (int nt = 0; nt < 4; ++nt) acc[mt][nt] = zero;

    const int kb = (lane >> 4) * 8;

    for (int k0 = 0; k0 < K_; k0 += 32) {
        __syncthreads();
        const ushort* ga = X + (size_t)(m0 + r0) * K_ + k0 + c8;
        gl_lds16(ga, Ast + tid * 8);
        gl_lds16(ga + (size_t)64 * K_, Ast + 2048 + tid * 8);
        const ushort* gb = W + (size_t)(n0 + r0) * K_ + k0 + c8;
        gl_lds16(gb, Bst + tid * 8);
        gl_lds16(gb + (size_t)64 * K_, Bst + 2048 + tid * 8);
        __syncthreads();

        short8 af[4], bf[4];
        #pragma unroll
        for (int mt = 0; mt < 4; ++mt)
            af[mt] = *(const short8*)(Ast + (wm * 64 + mt * 16 + (lane & 15)) * 32 + kb);
        #pragma unroll
        for (int nt = 0; nt < 4; ++nt)
            bf[nt] = *(const short8*)(Bst + (wn * 64 + nt * 16 + (lane & 15)) * 32 + kb);
        #pragma unroll
        for (int mt = 0; mt < 4; ++mt)
            #pragma unroll
            for (int nt = 0; nt < 4; ++nt) {
                if (SWAP)
                    acc[mt][nt] = __builtin_amdgcn_mfma_f32_16x16x32_bf16(bf[nt], af[mt], acc[mt][nt], 0, 0, 0);
                else
                    acc[mt][nt] = __builtin_amdgcn_mfma_f32_16x16x32_bf16(af[mt], bf[nt], acc[mt][nt], 0, 0, 0);
            }
    }
}

// ---------------------------------------------------------------------------
// QKV projections. z=0: Q -> [B,H,S,D] scaled by QSCALE (swapped, d-contig
// u16x4 stores). z=1: K -> [B,H,S,D] (swapped). z=2: V -> [B,H,D,S].
// ---------------------------------------------------------------------------
__global__ __launch_bounds__(256)
void gemm_qkv(const ushort* __restrict__ Xq, const ushort* __restrict__ Xk,
              const ushort* __restrict__ Xv, const ushort* __restrict__ Wq,
              const ushort* __restrict__ Wk, const ushort* __restrict__ Wv,
              const float* __restrict__ bq, const float* __restrict__ bk,
              const float* __restrict__ bv, ushort* __restrict__ Qh,
              ushort* __restrict__ Kh, ushort* __restrict__ Vt)
{
    __shared__ ushort Ast[128 * 32];
    __shared__ ushort Bst[128 * 32];
    const int z = blockIdx.z;
    const ushort* X = (z == 0) ? Xq : (z == 1) ? Xk : Xv;
    const ushort* W = (z == 0) ? Wq : (z == 1) ? Wk : Wv;
    const float* bias = (z == 0) ? bq : (z == 1) ? bk : bv;
    ushort* dst = (z == 0) ? Qh : (z == 1) ? Kh : Vt;

    const int m0 = blockIdx.y * 128, n0 = blockIdx.x * 128;
    f32x4 acc[4][4];
    const int lane = threadIdx.x & 63, w = threadIdx.x >> 6;
    const int wm = w & 1, wn = w >> 1;
    const int l15 = lane & 15, quad = lane >> 4;

    if (z < 2) {
        gemm_core<1>(X, W, m0, n0, acc, Ast, Bst);
        const float qsc = (z == 0) ? QSCALE : 1.0f;
        #pragma unroll
        for (int nt = 0; nt < 4; ++nt) {
            const int nb = n0 + wn * 64 + nt * 16 + quad * 4;   // feature dim
            const int h = nb >> 6, d0 = nb & 63;
            const float4 b4 = *(const float4*)(bias + nb);
            const float bb4[4] = {b4.x, b4.y, b4.z, b4.w};
            #pragma unroll
            for (int mt = 0; mt < 4; ++mt) {
                const int tok = m0 + wm * 64 + mt * 16 + l15;
                const int b = tok >> 11, s = tok & (S_ - 1);
                u16x4 pk;
                #pragma unroll
                for (int r = 0; r < 4; ++r)
                    pk[r] = f2bf((acc[mt][nt][r] + bb4[r]) * qsc);
                *(u16x4*)&dst[(((size_t)(b * H_ + h) * S_) + s) * D_ + d0] = pk;
            }
        }
    } else {
        gemm_core<0>(X, W, m0, n0, acc, Ast, Bst);
        float bias4[4];
        #pragma unroll
        for (int nt = 0; nt < 4; ++nt)
            bias4[nt] = bias[n0 + wn * 64 + nt * 16 + l15];
        #pragma unroll
        for (int mt = 0; mt < 4; ++mt) {
            const int mrow0 = m0 + wm * 64 + mt * 16 + (quad * 4);
            const int b = mrow0 >> 11;
            const int s0 = mrow0 & (S_ - 1);
            #pragma unroll
            for (int nt = 0; nt < 4; ++nt) {
                const int n = n0 + wn * 64 + nt * 16 + l15;
                const int h = n >> 6, d = n & 63;
                u16x4 pk;
                #pragma unroll
                for (int r = 0; r < 4; ++r) pk[r] = f2bf(acc[mt][nt][r] + bias4[nt]);
                *(u16x4*)&Vt[(((size_t)(b * H_ + h) * D_) + d) * S_ + s0] = pk;
            }
        }
    }
}

// ---------------------------------------------------------------------------
// Final projection: out(fp32) = AO . Wo^T + bo
// ---------------------------------------------------------------------------
__global__ __launch_bounds__(256)
void gemm_out(const ushort* __restrict__ X, const ushort* __restrict__ W,
              const float* __restrict__ bias, float* __restrict__ out)
{
    __shared__ ushort Ast[128 * 32];
    __shared__ ushort Bst[128 * 32];
    const int m0 = blockIdx.y * 128, n0 = blockIdx.x * 128;
    f32x4 acc[4][4];
    gemm_core<0>(X, W, m0, n0, acc, Ast, Bst);

    const int lane = threadIdx.x & 63, w = threadIdx.x >> 6;
    const int wm = w & 1, wn = w >> 1;
    float bias4[4];
    #pragma unroll
    for (int nt = 0; nt < 4; ++nt)
        bias4[nt] = bias[n0 + wn * 64 + nt * 16 + (lane & 15)];

    #pragma unroll
    for (int mt = 0; mt < 4; ++mt) {
        const int mrow0 = m0 + wm * 64 + mt * 16 + ((lane >> 4) * 4);
        #pragma unroll
        for (int nt = 0; nt < 4; ++nt) {
            const int n = n0 + wn * 64 + nt * 16 + (lane & 15);
            #pragma unroll
            for (int r = 0; r < 4; ++r)
                out[(size_t)(mrow0 + r) * E_ + n] = acc[mt][nt][r] + bias4[nt];
        }
    }
}

// ---------------------------------------------------------------------------
// Flash attention, PAIR-PV at launch_bounds(256,2). RETRY of R12 verbatim:
// R12 aborted at runtime but the only R11->R12 diff was the launch bound
// (pure regalloc change, no addressing change); buffer protocol re-audited
// race-free (every buf read completes before the barrier preceding its
// overwrite). Identical resubmit discriminates kernel fault vs infra flake.
// Pair-PV: kv loop unrolled by 2 tiles; tile A's p in A-frag k-slots 0..3,
// tile B's in 4..7 -> one full-K=32 PV MFMA set per pair (halves PV MFMAs).
// Coalesced gl_lds staging, 2 LDS buffers, 1 barrier per tile.
// No runtime indexing of per-thread arrays (scratch-demotion lesson).
// ---------------------------------------------------------------------------
#define NTILE (S_ / 64)
__global__ __launch_bounds__(256, 2)
void flash_mfma(const ushort* __restrict__ Qg, const ushort* __restrict__ Kg,
                const ushort* __restrict__ Vg, ushort* __restrict__ AO)
{
    // 40 KB: Qs(4096) | buf0: K(4096) V(4096) | buf1: K(4096) V(4096)
    __shared__ ushort sh[20480];
    ushort* Qs = sh;
    ushort* K0 = sh + 4096;
    ushort* V0 = sh + 8192;
    ushort* K1 = sh + 12288;
    ushort* V1 = sh + 16384;

    const int tid = threadIdx.x, lane = tid & 63, w = tid >> 6;
    const int l15 = lane & 15, quad = lane >> 4;
    const int q0 = blockIdx.x * 64, h = blockIdx.y, b = blockIdx.z;
    const size_t qk_off = (size_t)(b * H_ + h) * S_ * D_;   // [s][d]
    const size_t vt_off = (size_t)(b * H_ + h) * D_ * S_;   // [d][s]

    // ---- stage Q + K/V tile 0 (buf 0) together ----
    #pragma unroll
    for (int i = 0; i < 2; ++i) {
        const int chunk = w + i * 4;
        const int row = chunk * 8 + (lane >> 3);
        const int gcol = (lane & 7) ^ (row & 7);
        gl_lds16(Qg + qk_off + (size_t)(q0 + row) * D_ + gcol * 8,
                 Qs + chunk * 512 + lane * 8);
        gl_lds16(Kg + qk_off + (size_t)row * D_ + gcol * 8,
                 K0 + chunk * 512 + lane * 8);
        gl_lds16(Vg + vt_off + (size_t)row * S_ + gcol * 8,
                 V0 + chunk * 512 + lane * 8);
    }
    __syncthreads();

    // loop-invariant Q B-frags: qb[g][kt] for q-group g (rows g*16+l15)
    short8 qb[4][2];
    #pragma unroll
    for (int g = 0; g < 4; ++g)
        #pragma unroll
        for (int kt = 0; kt < 2; ++kt)
            qb[g][kt] = *(const short8*)&Qs[(g * 16 + l15) * 64 +
                                            (((kt * 4 + quad) ^ (l15 & 7)) * 8)];

    const f32x4 zero = {0.f, 0.f, 0.f, 0.f};
    f32x4 o[4][4];                         // o[g][nt]: O[q=g*16+quad*4+r][d=nt*16+l15]
    #pragma unroll
    for (int g = 0; g < 4; ++g)
        #pragma unroll
        for (int nt = 0; nt < 4; ++nt) o[g][nt] = zero;
    float lsum[4] = {0.f, 0.f, 0.f, 0.f};  // partial denom, q = g*16+l15

    const int krow = (w * 16 + l15) * 64;                // K frag row offset
    const int gidx = (2 * w + (quad >> 1)) ^ (l15 & 7);  // swizzled V group

    for (int jp = 0; jp < NTILE; jp += 2) {
        // ================= body A: tile jp (buf 0) =================
        short8 ka[2];
        #pragma unroll
        for (int kt = 0; kt < 2; ++kt)
            ka[kt] = *(const short8*)&K0[krow + (((kt * 4 + quad) ^ (l15 & 7)) * 8)];
        uint2 vvA[4];
        #pragma unroll
        for (int nt = 0; nt < 4; ++nt)
            vvA[nt] = *(const uint2*)&V0[(nt * 16 + l15) * 64 + gidx * 8 + (quad & 1) * 4];

        // prefetch tile jp+1 -> buf 1
        {
            const int j0n = (jp + 1) * 64;
            #pragma unroll
            for (int i = 0; i < 2; ++i) {
                const int chunk = w + i * 4;
                const int row = chunk * 8 + (lane >> 3);
                const int gcol = (lane & 7) ^ (row & 7);
                gl_lds16(Kg + qk_off + (size_t)(j0n + row) * D_ + gcol * 8,
                         K1 + chunk * 512 + lane * 8);
                gl_lds16(Vg + vt_off + (size_t)row * S_ + j0n + gcol * 8,
                         V1 + chunk * 512 + lane * 8);
            }
        }

        // QK A + exp + pack (lower half of pair A-frag)
        uint2 paLo[4];
        #pragma unroll
        for (int g = 0; g < 4; ++g) {
            f32x4 t;
            t = __builtin_amdgcn_mfma_f32_16x16x32_bf16(ka[0], qb[g][0], zero, 0, 0, 0);
            t = __builtin_amdgcn_mfma_f32_16x16x32_bf16(ka[1], qb[g][1], t, 0, 0, 0);
            const float p0 = EXP2F(t[0]), p1 = EXP2F(t[1]);
            const float p2 = EXP2F(t[2]), p3 = EXP2F(t[3]);
            lsum[g] += (p0 + p1) + (p2 + p3);
            const unsigned a0 = __float_as_uint(p0) + 0x8000u;
            const unsigned a1 = __float_as_uint(p1) + 0x8000u;
            const unsigned a2 = __float_as_uint(p2) + 0x8000u;
            const unsigned a3 = __float_as_uint(p3) + 0x8000u;
            paLo[g].x = (a1 & 0xffff0000u) | (a0 >> 16);
            paLo[g].y = (a3 & 0xffff0000u) | (a2 >> 16);
        }
        __syncthreads();   // buf1 loaded; everyone done with buf0

        // ================= body B: tile jp+1 (buf 1) =================
        #pragma unroll
        for (int kt = 0; kt < 2; ++kt)
            ka[kt] = *(const short8*)&K1[krow + (((kt * 4 + quad) ^ (l15 & 7)) * 8)];
        uint2 vvB[4];
        #pragma unroll
        for (int nt = 0; nt < 4; ++nt)
            vvB[nt] = *(const uint2*)&V1[(nt * 16 + l15) * 64 + gidx * 8 + (quad & 1) * 4];

        // prefetch tile jp+2 -> buf 0
        if (jp + 2 < NTILE) {
            const int j0n = (jp + 2) * 64;
            #pragma unroll
            for (int i = 0; i < 2; ++i) {
                const int chunk = w + i * 4;
                const int row = chunk * 8 + (lane >> 3);
                const int gcol = (lane & 7) ^ (row & 7);
                gl_lds16(Kg + qk_off + (size_t)(j0n + row) * D_ + gcol * 8,
                         K0 + chunk * 512 + lane * 8);
                gl_lds16(Vg + vt_off + (size_t)row * S_ + j0n + gcol * 8,
                         V0 + chunk * 512 + lane * 8);
            }
        }

        // QK B + exp + pack upper; assemble full-K pair A-frags
        short8 pa8[4];
        #pragma unroll
        for (int g = 0; g < 4; ++g) {
            f32x4 t;
            t = __builtin_amdgcn_mfma_f32_16x16x32_bf16(ka[0], qb[g][0], zero, 0, 0, 0);
            t = __builtin_amdgcn_mfma_f32_16x16x32_bf16(ka[1], qb[g][1], t, 0, 0, 0);
            const float p0 = EXP2F(t[0]), p1 = EXP2F(t[1]);
            const float p2 = EXP2F(t[2]), p3 = EXP2F(t[3]);
            lsum[g] += (p0 + p1) + (p2 + p3);
            const unsigned a0 = __float_as_uint(p0) + 0x8000u;
            const unsigned a1 = __float_as_uint(p1) + 0x8000u;
            const unsigned a2 = __float_as_uint(p2) + 0x8000u;
            const unsigned a3 = __float_as_uint(p3) + 0x8000u;
            u32x4 pk;
            pk[0] = paLo[g].x;
            pk[1] = paLo[g].y;
            pk[2] = (a1 & 0xffff0000u) | (a0 >> 16);
            pk[3] = (a3 & 0xffff0000u) | (a2 >> 16);
            pa8[g] = __builtin_bit_cast(short8, pk);
        }

        // PV (full K=32): vb = {V_A rows (k=0..3 slots), V_B rows (k=4..7)}
        #pragma unroll
        for (int nt = 0; nt < 4; ++nt) {
            u32x4 vk;
            vk[0] = vvA[nt].x; vk[1] = vvA[nt].y;
            vk[2] = vvB[nt].x; vk[3] = vvB[nt].y;
            const short8 vb8 = __builtin_bit_cast(short8, vk);
            #pragma unroll
            for (int g = 0; g < 4; ++g)
                o[g][nt] = __builtin_amdgcn_mfma_f32_16x16x32_bf16(pa8[g], vb8, o[g][nt], 0, 0, 0);
        }

        __syncthreads();   // buf0 (tile jp+2) loaded; everyone done with buf1
    }

    // ---- cross-wave reduction of O and l (kv was split across waves) ----
    #pragma unroll
    for (int g = 0; g < 4; ++g) {
        lsum[g] += __shfl_xor(lsum[g], 16);
        lsum[g] += __shfl_xor(lsum[g], 32);   // now quad-uniform
    }
    __syncthreads();
    float* fb = (float*)sh;                   // 10240 floats available
    #pragma unroll
    for (int g = 0; g < 4; ++g) {
        if (w != g) {
            #pragma unroll
            for (int nt = 0; nt < 4; ++nt)
                #pragma unroll
                for (int r = 0; r < 4; ++r)
                    fb[w * 1024 + (nt * 4 + r) * 64 + lane] = o[g][nt][r];
            if (quad == 0) fb[4096 + w * 64 + l15] = lsum[g];
        }
        __syncthreads();
        if (w == g) {
            #pragma unroll
            for (int ws = 0; ws < 4; ++ws) {
                if (ws == g) continue;
                #pragma unroll
                for (int nt = 0; nt < 4; ++nt)
                    #pragma unroll
                    for (int r = 0; r < 4; ++r)
                        o[g][nt][r] += fb[ws * 1024 + (nt * 4 + r) * 64 + lane];
                lsum[g] += fb[4096 + ws * 64 + l15];
            }
        }
        __syncthreads();
    }

    // Final store: wave g owns o[g]; wave-uniform branch, compile-time indices.
    #pragma unroll
    for (int g = 0; g < 4; ++g) {
        if (w == g) {
            const float inv = 1.0f / lsum[g];     // q = g*16 + l15
            float invr[4];
            #pragma unroll
            for (int r = 0; r < 4; ++r)
                invr[r] = __shfl(inv, (lane & 0x30) | (quad * 4 + r));
            #pragma unroll
            for (int nt = 0; nt < 4; ++nt) {
                const int e = h * 64 + nt * 16 + l15;
                #pragma unroll
                for (int r = 0; r < 4; ++r) {
                    const int s = q0 + g * 16 + quad * 4 + r;
                    AO[(size_t)(b * S_ + s) * E_ + e] = f2bf(o[g][nt][r] * invr[r]);
                }
            }
        }
    }
}

// ---------------------------------------------------------------------------
extern "C" void kernel_launch(void* const* d_in, const int* in_sizes, int n_in,
                              void* d_out, int out_size, void* d_ws, size_t ws_size,
                              hipStream_t stream) {
    const float* query = (const float*)d_in[0];
    const float* key   = (const float*)d_in[1];
    const float* value = (const float*)d_in[2];
    const float* Wq = (const float*)d_in[3];
    const float* bq = (const float*)d_in[4];
    const float* Wk = (const float*)d_in[5];
    const float* bk = (const float*)d_in[6];
    const float* Wv = (const float*)d_in[7];
    const float* bv = (const float*)d_in[8];
    const float* Wo = (const float*)d_in[9];
    const float* bo = (const float*)d_in[10];
    float* out = (float*)d_out;

    ushort* ws = (ushort*)d_ws;
    ushort* Xq  = ws;
    ushort* Xk  = ws + 4194304u;
    ushort* Xv  = ws + 8388608u;
    ushort* Wqb = ws + 12582912u;
    ushort* Wkb = ws + 13631488u;
    ushort* Wvb = ws + 14680064u;
    ushort* Wob = ws + 15728640u;
    ushort* Qh  = ws + 16777216u;          // [B,H,S,D] (pre-scaled by QSCALE)
    ushort* Kh  = ws + 20971520u;          // [B,H,S,D]
    ushort* Vt  = ws + 25165824u;          // [B,H,D,S]
    ushort* AO  = ws + 29360128u;          // [B,S,E]

    cvt_all<<<8192, 256, 0, stream>>>(query, key, value, Wq, Wk, Wv, Wo, ws);
    gemm_qkv<<<dim3(8, 32, 3), 256, 0, stream>>>(Xq, Xk, Xv, Wqb, Wkb, Wvb,
                                                 bq, bk, bv, Qh, Kh, Vt);
    flash_mfma<<<dim3(32, 16, 2), 256, 0, stream>>>(Qh, Kh, Vt, AO);
    gemm_out<<<dim3(8, 32, 1), 256, 0, stream>>>(AO, Wob, bo, out);
}

// Round 14
// 232.158 us; speedup vs baseline: 1.3274x; 1.0046x over previous
//
#include <hip/hip_runtime.h>

#define B_ 2
#define S_ 2048
#define E_ 1024
#define H_ 16
#define D_ 64
#define M_ (B_*S_)
#define K_ E_

typedef __attribute__((ext_vector_type(8))) short  short8;
typedef __attribute__((ext_vector_type(4))) float  f32x4;
typedef __attribute__((ext_vector_type(8))) unsigned short u16x8;
typedef __attribute__((ext_vector_type(4))) unsigned short u16x4;
typedef __attribute__((ext_vector_type(4))) unsigned int   u32x4;

// 0.125 * log2(e): folded into Q so scores arrive in exp2 domain
#define QSCALE 0.18033688011112042f

#if __has_builtin(__builtin_amdgcn_exp2f)
#define EXP2F(x) __builtin_amdgcn_exp2f(x)   // raw v_exp_f32 (R10: -18% VALUBusy)
#else
#define EXP2F(x) exp2f(x)
#endif

__device__ __forceinline__ unsigned short f2bf(float f) {   // RNE
    unsigned u = __float_as_uint(f);
    u += 0x7fffu + ((u >> 16) & 1u);
    return (unsigned short)(u >> 16);
}

__device__ __forceinline__ void gl_lds16(const ushort* g, ushort* l) {
    __builtin_amdgcn_global_load_lds((const __attribute__((address_space(1))) void*)g,
                                     (__attribute__((address_space(3))) void*)l,
                                     16, 0, 0);
}

// ---------------------------------------------------------------------------
// fp32 -> bf16 conversion (all inputs).
// ---------------------------------------------------------------------------
__global__ __launch_bounds__(256)
void cvt_all(const float* __restrict__ q, const float* __restrict__ k,
             const float* __restrict__ v, const float* __restrict__ wq,
             const float* __restrict__ wk, const float* __restrict__ wv,
             const float* __restrict__ wo, ushort* __restrict__ dst)
{
    const int bid = blockIdx.x;
    const float* src;
    size_t dof;
    int local;
    if (bid < 6144) {
        const int t = bid >> 11;
        src = (t == 0) ? q : (t == 1) ? k : v;
        dof = (size_t)t * 4194304u;
        local = bid & 2047;
    } else {
        const int r = bid - 6144;
        const int t = r >> 9;
        src = (t == 0) ? wq : (t == 1) ? wk : (t == 2) ? wv : wo;
        dof = 12582912u + (size_t)t * 1048576u;
        local = r & 511;
    }
    const size_t idx = (size_t)local * 2048 + threadIdx.x * 8;
    const float4 a = *(const float4*)(src + idx);
    const float4 b = *(const float4*)(src + idx + 4);
    u16x8 o;
    o[0] = f2bf(a.x); o[1] = f2bf(a.y); o[2] = f2bf(a.z); o[3] = f2bf(a.w);
    o[4] = f2bf(b.x); o[5] = f2bf(b.y); o[6] = f2bf(b.z); o[7] = f2bf(b.w);
    *(u16x8*)(dst + dof + idx) = o;
}

// ---------------------------------------------------------------------------
// m97 GEMM core (128x128, BK=32). SWAP=0: acc = X.W^T. SWAP=1: swapped.
// ---------------------------------------------------------------------------
template<int SWAP>
__device__ __forceinline__ void gemm_core(const ushort* __restrict__ X,
                                          const ushort* __restrict__ W,
                                          int m0, int n0,
                                          f32x4 acc[4][4],
                                          ushort* Ast, ushort* Bst)
{
    const int tid  = threadIdx.x;
    const int lane = tid & 63;
    const int w    = tid >> 6;
    const int wm   = w & 1, wn = w >> 1;
    const int r0   = tid >> 2;
    const int c8   = (tid & 3) * 8;

    const f32x4 zero = {0.f, 0.f, 0.f, 0.f};
    #pragma unroll
    for (int mt = 0; mt < 4; ++mt)
        #pragma unroll
        for (int nt = 0; nt < 4; ++nt) acc[mt][nt] = zero;

    const int kb = (lane >> 4) * 8;

    for (int k0 = 0; k0 < K_; k0 += 32) {
        __syncthreads();
        const ushort* ga = X + (size_t)(m0 + r0) * K_ + k0 + c8;
        gl_lds16(ga, Ast + tid * 8);
        gl_lds16(ga + (size_t)64 * K_, Ast + 2048 + tid * 8);
        const ushort* gb = W + (size_t)(n0 + r0) * K_ + k0 + c8;
        gl_lds16(gb, Bst + tid * 8);
        gl_lds16(gb + (size_t)64 * K_, Bst + 2048 + tid * 8);
        __syncthreads();

        short8 af[4], bf[4];
        #pragma unroll
        for (int mt = 0; mt < 4; ++mt)
            af[mt] = *(const short8*)(Ast + (wm * 64 + mt * 16 + (lane & 15)) * 32 + kb);
        #pragma unroll
        for (int nt = 0; nt < 4; ++nt)
            bf[nt] = *(const short8*)(Bst + (wn * 64 + nt * 16 + (lane & 15)) * 32 + kb);
        #pragma unroll
        for (int mt = 0; mt < 4; ++mt)
            #pragma unroll
            for (int nt = 0; nt < 4; ++nt) {
                if (SWAP)
                    acc[mt][nt] = __builtin_amdgcn_mfma_f32_16x16x32_bf16(bf[nt], af[mt], acc[mt][nt], 0, 0, 0);
                else
                    acc[mt][nt] = __builtin_amdgcn_mfma_f32_16x16x32_bf16(af[mt], bf[nt], acc[mt][nt], 0, 0, 0);
            }
    }
}

// ---------------------------------------------------------------------------
// QKV projections. z=0: Q -> [B,H,S,D] scaled by QSCALE (swapped, d-contig
// u16x4 stores). z=1: K -> [B,H,S,D] (swapped). z=2: V -> [B,H,D,S].
// ---------------------------------------------------------------------------
__global__ __launch_bounds__(256)
void gemm_qkv(const ushort* __restrict__ Xq, const ushort* __restrict__ Xk,
              const ushort* __restrict__ Xv, const ushort* __restrict__ Wq,
              const ushort* __restrict__ Wk, const ushort* __restrict__ Wv,
              const float* __restrict__ bq, const float* __restrict__ bk,
              const float* __restrict__ bv, ushort* __restrict__ Qh,
              ushort* __restrict__ Kh, ushort* __restrict__ Vt)
{
    __shared__ ushort Ast[128 * 32];
    __shared__ ushort Bst[128 * 32];
    const int z = blockIdx.z;
    const ushort* X = (z == 0) ? Xq : (z == 1) ? Xk : Xv;
    const ushort* W = (z == 0) ? Wq : (z == 1) ? Wk : Wv;
    const float* bias = (z == 0) ? bq : (z == 1) ? bk : bv;
    ushort* dst = (z == 0) ? Qh : (z == 1) ? Kh : Vt;

    const int m0 = blockIdx.y * 128, n0 = blockIdx.x * 128;
    f32x4 acc[4][4];
    const int lane = threadIdx.x & 63, w = threadIdx.x >> 6;
    const int wm = w & 1, wn = w >> 1;
    const int l15 = lane & 15, quad = lane >> 4;

    if (z < 2) {
        gemm_core<1>(X, W, m0, n0, acc, Ast, Bst);
        const float qsc = (z == 0) ? QSCALE : 1.0f;
        #pragma unroll
        for (int nt = 0; nt < 4; ++nt) {
            const int nb = n0 + wn * 64 + nt * 16 + quad * 4;   // feature dim
            const int h = nb >> 6, d0 = nb & 63;
            const float4 b4 = *(const float4*)(bias + nb);
            const float bb4[4] = {b4.x, b4.y, b4.z, b4.w};
            #pragma unroll
            for (int mt = 0; mt < 4; ++mt) {
                const int tok = m0 + wm * 64 + mt * 16 + l15;
                const int b = tok >> 11, s = tok & (S_ - 1);
                u16x4 pk;
                #pragma unroll
                for (int r = 0; r < 4; ++r)
                    pk[r] = f2bf((acc[mt][nt][r] + bb4[r]) * qsc);
                *(u16x4*)&dst[(((size_t)(b * H_ + h) * S_) + s) * D_ + d0] = pk;
            }
        }
    } else {
        gemm_core<0>(X, W, m0, n0, acc, Ast, Bst);
        float bias4[4];
        #pragma unroll
        for (int nt = 0; nt < 4; ++nt)
            bias4[nt] = bias[n0 + wn * 64 + nt * 16 + l15];
        #pragma unroll
        for (int mt = 0; mt < 4; ++mt) {
            const int mrow0 = m0 + wm * 64 + mt * 16 + (quad * 4);
            const int b = mrow0 >> 11;
            const int s0 = mrow0 & (S_ - 1);
            #pragma unroll
            for (int nt = 0; nt < 4; ++nt) {
                const int n = n0 + wn * 64 + nt * 16 + l15;
                const int h = n >> 6, d = n & 63;
                u16x4 pk;
                #pragma unroll
                for (int r = 0; r < 4; ++r) pk[r] = f2bf(acc[mt][nt][r] + bias4[nt]);
                *(u16x4*)&Vt[(((size_t)(b * H_ + h) * D_) + d) * S_ + s0] = pk;
            }
        }
    }
}

// ---------------------------------------------------------------------------
// Final projection: out(fp32) = AO . Wo^T + bo.
// 128x64 tile (512 blocks = 2/CU): the 128x128 grid was exactly 1 block/CU,
// leaving zero cross-block cover for the K-loop barrier drain.
// ---------------------------------------------------------------------------
__global__ __launch_bounds__(256)
void gemm_out(const ushort* __restrict__ X, const ushort* __restrict__ W,
              const float* __restrict__ bias, float* __restrict__ out)
{
    __shared__ ushort Ast[128 * 32];   // 8 KB
    __shared__ ushort Bst[64 * 32];    // 4 KB
    const int m0 = blockIdx.y * 128, n0 = blockIdx.x * 64;
    const int tid = threadIdx.x, lane = tid & 63, w = tid >> 6;
    const int wm = w & 1, wn = w >> 1;
    const int l15 = lane & 15, quad = lane >> 4;
    const int r0 = tid >> 2, c8 = (tid & 3) * 8;
    const int kb = quad * 8;

    const f32x4 zero = {0.f, 0.f, 0.f, 0.f};
    f32x4 acc[4][2];
    #pragma unroll
    for (int mt = 0; mt < 4; ++mt)
        #pragma unroll
        for (int nt = 0; nt < 2; ++nt) acc[mt][nt] = zero;

    for (int k0 = 0; k0 < K_; k0 += 32) {
        __syncthreads();
        const ushort* ga = X + (size_t)(m0 + r0) * K_ + k0 + c8;
        gl_lds16(ga, Ast + tid * 8);
        gl_lds16(ga + (size_t)64 * K_, Ast + 2048 + tid * 8);
        const ushort* gb = W + (size_t)(n0 + r0) * K_ + k0 + c8;
        gl_lds16(gb, Bst + tid * 8);
        __syncthreads();

        short8 af[4], bf[2];
        #pragma unroll
        for (int mt = 0; mt < 4; ++mt)
            af[mt] = *(const short8*)(Ast + (wm * 64 + mt * 16 + l15) * 32 + kb);
        #pragma unroll
        for (int nt = 0; nt < 2; ++nt)
            bf[nt] = *(const short8*)(Bst + (wn * 32 + nt * 16 + l15) * 32 + kb);
        #pragma unroll
        for (int mt = 0; mt < 4; ++mt)
            #pragma unroll
            for (int nt = 0; nt < 2; ++nt)
                acc[mt][nt] = __builtin_amdgcn_mfma_f32_16x16x32_bf16(af[mt], bf[nt], acc[mt][nt], 0, 0, 0);
    }

    float bias2[2];
    #pragma unroll
    for (int nt = 0; nt < 2; ++nt)
        bias2[nt] = bias[n0 + wn * 32 + nt * 16 + l15];

    #pragma unroll
    for (int mt = 0; mt < 4; ++mt) {
        const int mrow0 = m0 + wm * 64 + mt * 16 + quad * 4;
        #pragma unroll
        for (int nt = 0; nt < 2; ++nt) {
            const int n = n0 + wn * 32 + nt * 16 + l15;
            #pragma unroll
            for (int r = 0; r < 4; ++r)
                out[(size_t)(mrow0 + r) * E_ + n] = acc[mt][nt][r] + bias2[nt];
        }
    }
}

// ---------------------------------------------------------------------------
// Flash attention, PAIR-PV at launch_bounds(256,3) with Q frags re-read from
// LDS each body (drops the 32-reg qb cache; Qs stays resident all loop).
// Live regs ~140 < 170 cap -> 3 blocks/CU (R11 spilled at this cap WITH the
// qb cache; this is the de-pressurized retry). Spill guard: WRITE_SIZE.
// Pair-PV: tile A's p in A-frag k-slots 0..3, tile B's in 4..7 -> one
// full-K=32 PV MFMA set per pair. Coalesced gl_lds, 2 buffers, 1 barrier/tile.
// No runtime indexing of per-thread arrays (scratch-demotion lesson).
// ---------------------------------------------------------------------------
#define NTILE (S_ / 64)
__global__ __launch_bounds__(256, 3)
void flash_mfma(const ushort* __restrict__ Qg, const ushort* __restrict__ Kg,
                const ushort* __restrict__ Vg, ushort* __restrict__ AO)
{
    // 40 KB: Qs(4096) | buf0: K(4096) V(4096) | buf1: K(4096) V(4096)
    __shared__ ushort sh[20480];
    ushort* Qs = sh;
    ushort* K0 = sh + 4096;
    ushort* V0 = sh + 8192;
    ushort* K1 = sh + 12288;
    ushort* V1 = sh + 16384;

    const int tid = threadIdx.x, lane = tid & 63, w = tid >> 6;
    const int l15 = lane & 15, quad = lane >> 4;
    const int q0 = blockIdx.x * 64, h = blockIdx.y, b = blockIdx.z;
    const size_t qk_off = (size_t)(b * H_ + h) * S_ * D_;   // [s][d]
    const size_t vt_off = (size_t)(b * H_ + h) * D_ * S_;   // [d][s]

    // ---- stage Q + K/V tile 0 (buf 0) together ----
    #pragma unroll
    for (int i = 0; i < 2; ++i) {
        const int chunk = w + i * 4;
        const int row = chunk * 8 + (lane >> 3);
        const int gcol = (lane & 7) ^ (row & 7);
        gl_lds16(Qg + qk_off + (size_t)(q0 + row) * D_ + gcol * 8,
                 Qs + chunk * 512 + lane * 8);
        gl_lds16(Kg + qk_off + (size_t)row * D_ + gcol * 8,
                 K0 + chunk * 512 + lane * 8);
        gl_lds16(Vg + vt_off + (size_t)row * S_ + gcol * 8,
                 V0 + chunk * 512 + lane * 8);
    }
    __syncthreads();

    const f32x4 zero = {0.f, 0.f, 0.f, 0.f};
    f32x4 o[4][4];                         // o[g][nt]: O[q=g*16+quad*4+r][d=nt*16+l15]
    #pragma unroll
    for (int g = 0; g < 4; ++g)
        #pragma unroll
        for (int nt = 0; nt < 4; ++nt) o[g][nt] = zero;
    float lsum[4] = {0.f, 0.f, 0.f, 0.f};  // partial denom, q = g*16+l15

    const int krow = (w * 16 + l15) * 64;                // K frag row offset
    const int gidx = (2 * w + (quad >> 1)) ^ (l15 & 7);  // swizzled V group

    for (int jp = 0; jp < NTILE; jp += 2) {
        // ================= body A: tile jp (buf 0) =================
        short8 ka[2];
        #pragma unroll
        for (int kt = 0; kt < 2; ++kt)
            ka[kt] = *(const short8*)&K0[krow + (((kt * 4 + quad) ^ (l15 & 7)) * 8)];
        uint2 vvA[4];
        #pragma unroll
        for (int nt = 0; nt < 4; ++nt)
            vvA[nt] = *(const uint2*)&V0[(nt * 16 + l15) * 64 + gidx * 8 + (quad & 1) * 4];

        // prefetch tile jp+1 -> buf 1
        {
            const int j0n = (jp + 1) * 64;
            #pragma unroll
            for (int i = 0; i < 2; ++i) {
                const int chunk = w + i * 4;
                const int row = chunk * 8 + (lane >> 3);
                const int gcol = (lane & 7) ^ (row & 7);
                gl_lds16(Kg + qk_off + (size_t)(j0n + row) * D_ + gcol * 8,
                         K1 + chunk * 512 + lane * 8);
                gl_lds16(Vg + vt_off + (size_t)row * S_ + j0n + gcol * 8,
                         V1 + chunk * 512 + lane * 8);
            }
        }

        // QK A + exp + pack (lower half of pair A-frag); Q frags from LDS
        uint2 paLo[4];
        #pragma unroll
        for (int g = 0; g < 4; ++g) {
            const short8 qg0 = *(const short8*)&Qs[(g * 16 + l15) * 64 +
                                                   ((quad ^ (l15 & 7)) * 8)];
            const short8 qg1 = *(const short8*)&Qs[(g * 16 + l15) * 64 +
                                                   (((4 + quad) ^ (l15 & 7)) * 8)];
            f32x4 t;
            t = __builtin_amdgcn_mfma_f32_16x16x32_bf16(ka[0], qg0, zero, 0, 0, 0);
            t = __builtin_amdgcn_mfma_f32_16x16x32_bf16(ka[1], qg1, t, 0, 0, 0);
            const float p0 = EXP2F(t[0]), p1 = EXP2F(t[1]);
            const float p2 = EXP2F(t[2]), p3 = EXP2F(t[3]);
            lsum[g] += (p0 + p1) + (p2 + p3);
            const unsigned a0 = __float_as_uint(p0) + 0x8000u;
            const unsigned a1 = __float_as_uint(p1) + 0x8000u;
            const unsigned a2 = __float_as_uint(p2) + 0x8000u;
            const unsigned a3 = __float_as_uint(p3) + 0x8000u;
            paLo[g].x = (a1 & 0xffff0000u) | (a0 >> 16);
            paLo[g].y = (a3 & 0xffff0000u) | (a2 >> 16);
        }
        __syncthreads();   // buf1 loaded; everyone done with buf0

        // ================= body B: tile jp+1 (buf 1) =================
        #pragma unroll
        for (int kt = 0; kt < 2; ++kt)
            ka[kt] = *(const short8*)&K1[krow + (((kt * 4 + quad) ^ (l15 & 7)) * 8)];
        uint2 vvB[4];
        #pragma unroll
        for (int nt = 0; nt < 4; ++nt)
            vvB[nt] = *(const uint2*)&V1[(nt * 16 + l15) * 64 + gidx * 8 + (quad & 1) * 4];

        // prefetch tile jp+2 -> buf 0
        if (jp + 2 < NTILE) {
            const int j0n = (jp + 2) * 64;
            #pragma unroll
            for (int i = 0; i < 2; ++i) {
                const int chunk = w + i * 4;
                const int row = chunk * 8 + (lane >> 3);
                const int gcol = (lane & 7) ^ (row & 7);
                gl_lds16(Kg + qk_off + (size_t)(j0n + row) * D_ + gcol * 8,
                         K0 + chunk * 512 + lane * 8);
                gl_lds16(Vg + vt_off + (size_t)row * S_ + j0n + gcol * 8,
                         V0 + chunk * 512 + lane * 8);
            }
        }

        // QK B + exp + pack upper; assemble full-K pair A-frags
        short8 pa8[4];
        #pragma unroll
        for (int g = 0; g < 4; ++g) {
            const short8 qg0 = *(const short8*)&Qs[(g * 16 + l15) * 64 +
                                                   ((quad ^ (l15 & 7)) * 8)];
            const short8 qg1 = *(const short8*)&Qs[(g * 16 + l15) * 64 +
                                                   (((4 + quad) ^ (l15 & 7)) * 8)];
            f32x4 t;
            t = __builtin_amdgcn_mfma_f32_16x16x32_bf16(ka[0], qg0, zero, 0, 0, 0);
            t = __builtin_amdgcn_mfma_f32_16x16x32_bf16(ka[1], qg1, t, 0, 0, 0);
            const float p0 = EXP2F(t[0]), p1 = EXP2F(t[1]);
            const float p2 = EXP2F(t[2]), p3 = EXP2F(t[3]);
            lsum[g] += (p0 + p1) + (p2 + p3);
            const unsigned a0 = __float_as_uint(p0) + 0x8000u;
            const unsigned a1 = __float_as_uint(p1) + 0x8000u;
            const unsigned a2 = __float_as_uint(p2) + 0x8000u;
            const unsigned a3 = __float_as_uint(p3) + 0x8000u;
            u32x4 pk;
            pk[0] = paLo[g].x;
            pk[1] = paLo[g].y;
            pk[2] = (a1 & 0xffff0000u) | (a0 >> 16);
            pk[3] = (a3 & 0xffff0000u) | (a2 >> 16);
            pa8[g] = __builtin_bit_cast(short8, pk);
        }

        // PV (full K=32): vb = {V_A rows (k=0..3 slots), V_B rows (k=4..7)}
        #pragma unroll
        for (int nt = 0; nt < 4; ++nt) {
            u32x4 vk;
            vk[0] = vvA[nt].x; vk[1] = vvA[nt].y;
            vk[2] = vvB[nt].x; vk[3] = vvB[nt].y;
            const short8 vb8 = __builtin_bit_cast(short8, vk);
            #pragma unroll
            for (int g = 0; g < 4; ++g)
                o[g][nt] = __builtin_amdgcn_mfma_f32_16x16x32_bf16(pa8[g], vb8, o[g][nt], 0, 0, 0);
        }

        __syncthreads();   // buf0 (tile jp+2) loaded; everyone done with buf1
    }

    // ---- cross-wave reduction of O and l (kv was split across waves) ----
    #pragma unroll
    for (int g = 0; g < 4; ++g) {
        lsum[g] += __shfl_xor(lsum[g], 16);
        lsum[g] += __shfl_xor(lsum[g], 32);   // now quad-uniform
    }
    __syncthreads();
    float* fb = (float*)sh;                   // 10240 floats available
    #pragma unroll
    for (int g = 0; g < 4; ++g) {
        if (w != g) {
            #pragma unroll
            for (int nt = 0; nt < 4; ++nt)
                #pragma unroll
                for (int r = 0; r < 4; ++r)
                    fb[w * 1024 + (nt * 4 + r) * 64 + lane] = o[g][nt][r];
            if (quad == 0) fb[4096 + w * 64 + l15] = lsum[g];
        }
        __syncthreads();
        if (w == g) {
            #pragma unroll
            for (int ws = 0; ws < 4; ++ws) {
                if (ws == g) continue;
                #pragma unroll
                for (int nt = 0; nt < 4; ++nt)
                    #pragma unroll
                    for (int r = 0; r < 4; ++r)
                        o[g][nt][r] += fb[ws * 1024 + (nt * 4 + r) * 64 + lane];
                lsum[g] += fb[4096 + ws * 64 + l15];
            }
        }
        __syncthreads();
    }

    // Final store: wave g owns o[g]; wave-uniform branch, compile-time indices.
    #pragma unroll
    for (int g = 0; g < 4; ++g) {
        if (w == g) {
            const float inv = 1.0f / lsum[g];     // q = g*16 + l15
            float invr[4];
            #pragma unroll
            for (int r = 0; r < 4; ++r)
                invr[r] = __shfl(inv, (lane & 0x30) | (quad * 4 + r));
            #pragma unroll
            for (int nt = 0; nt < 4; ++nt) {
                const int e = h * 64 + nt * 16 + l15;
                #pragma unroll
                for (int r = 0; r < 4; ++r) {
                    const int s = q0 + g * 16 + quad * 4 + r;
                    AO[(size_t)(b * S_ + s) * E_ + e] = f2bf(o[g][nt][r] * invr[r]);
                }
            }
        }
    }
}

// ---------------------------------------------------------------------------
extern "C" void kernel_launch(void* const* d_in, const int* in_sizes, int n_in,
                              void* d_out, int out_size, void* d_ws, size_t ws_size,
                              hipStream_t stream) {
    const float* query = (const float*)d_in[0];
    const float* key   = (const float*)d_in[1];
    const float* value = (const float*)d_in[2];
    const float* Wq = (const float*)d_in[3];
    const float* bq = (const float*)d_in[4];
    const float* Wk = (const float*)d_in[5];
    const float* bk = (const float*)d_in[6];
    const float* Wv = (const float*)d_in[7];
    const float* bv = (const float*)d_in[8];
    const float* Wo = (const float*)d_in[9];
    const float* bo = (const float*)d_in[10];
    float* out = (float*)d_out;

    ushort* ws = (ushort*)d_ws;
    ushort* Xq  = ws;
    ushort* Xk  = ws + 4194304u;
    ushort* Xv  = ws + 8388608u;
    ushort* Wqb = ws + 12582912u;
    ushort* Wkb = ws + 13631488u;
    ushort* Wvb = ws + 14680064u;
    ushort* Wob = ws + 15728640u;
    ushort* Qh  = ws + 16777216u;          // [B,H,S,D] (pre-scaled by QSCALE)
    ushort* Kh  = ws + 20971520u;          // [B,H,S,D]
    ushort* Vt  = ws + 25165824u;          // [B,H,D,S]
    ushort* AO  = ws + 29360128u;          // [B,S,E]

    cvt_all<<<8192, 256, 0, stream>>>(query, key, value, Wq, Wk, Wv, Wo, ws);
    gemm_qkv<<<dim3(8, 32, 3), 256, 0, stream>>>(Xq, Xk, Xv, Wqb, Wkb, Wvb,
                                                 bq, bk, bv, Qh, Kh, Vt);
    flash_mfma<<<dim3(32, 16, 2), 256, 0, stream>>>(Qh, Kh, Vt, AO);
    gemm_out<<<dim3(16, 32), 256, 0, stream>>>(AO, Wob, bo, out);
}